// Round 7
// baseline (50402.005 us; speedup 1.0000x reference)
//
#include <hip/hip_runtime.h>
#include <hip/hip_bf16.h>
#include <math.h>

#define B_SZ 128
#define T_SZ 2048
#define NI 512
#define NH 512

// ---------------------------------------------------------------------------
// Kernel 0: pack W_hh into bf16-pair, k-blocked layout in d_ws.
//   wt3[kk4*512 + j] (uint4), dword q (0..3) = pack( bf16(W[8kk4+2q][j]),
//                                                    bf16(W[8kk4+2q+1][j]) )
// ---------------------------------------------------------------------------
__device__ __forceinline__ unsigned bf16_rne(float f) {
    unsigned u = __float_as_uint(f);
    return (u + 0x7fffu + ((u >> 16) & 1u)) >> 16;   // round-nearest-even
}

__global__ __launch_bounds__(256) void pack_whh(
    const float* __restrict__ W, uint4* __restrict__ wt3)
{
    const int idx = blockIdx.x * 256 + threadIdx.x;  // = kk4*512 + j
    const int j   = idx & 511;
    const int kk4 = idx >> 9;
    const int k0  = kk4 * 8;
    unsigned d[4];
    #pragma unroll
    for (int q = 0; q < 4; ++q) {
        const unsigned lo = bf16_rne(W[(size_t)(k0 + 2 * q)     * NH + j]);
        const unsigned hi = bf16_rne(W[(size_t)(k0 + 2 * q + 1) * NH + j]);
        d[q] = lo | (hi << 16);
    }
    wt3[idx] = make_uint4(d[0], d[1], d[2], d[3]);
}

// ---------------------------------------------------------------------------
// Kernel 1: x_proj = inputs @ W_xh + b_h, in-place into d_out's outs region.
// ~84% of fp32 VALU roofline -- unchanged since round 1.
// ---------------------------------------------------------------------------
#define BM 64
#define BN 64
#define BK 16

__global__ __launch_bounds__(256) void proj_gemm(
    const float* __restrict__ A,      // inputs [M=B*T, K=NI]
    const float* __restrict__ W,      // W_xh [K, N]
    const float* __restrict__ bias,   // b_h [N]
    float* __restrict__ C)            // d_out outs region [M, N]
{
    __shared__ float As[BK][BM];
    __shared__ float Bs[BK][BN];
    const int m0 = blockIdx.y * BM;
    const int n0 = blockIdx.x * BN;
    const int tid = threadIdx.x;
    const int tx = tid & 15;
    const int ty = tid >> 4;

    const int ar = tid >> 2;
    const int ac = (tid & 3) * 4;
    const int bk = tid >> 4;
    const int bn = (tid & 15) * 4;

    float acc[4][4] = {};

    for (int k0 = 0; k0 < NI; k0 += BK) {
        float4 av = *reinterpret_cast<const float4*>(
            &A[(size_t)(m0 + ar) * NI + k0 + ac]);
        float4 bv = *reinterpret_cast<const float4*>(
            &W[(size_t)(k0 + bk) * NH + n0 + bn]);
        __syncthreads();
        As[ac + 0][ar] = av.x;
        As[ac + 1][ar] = av.y;
        As[ac + 2][ar] = av.z;
        As[ac + 3][ar] = av.w;
        *reinterpret_cast<float4*>(&Bs[bk][bn]) = bv;
        __syncthreads();
        #pragma unroll
        for (int kk = 0; kk < BK; ++kk) {
            float a[4], b[4];
            #pragma unroll
            for (int i = 0; i < 4; ++i) a[i] = As[kk][ty * 4 + i];
            #pragma unroll
            for (int jj = 0; jj < 4; ++jj) b[jj] = Bs[kk][tx * 4 + jj];
            #pragma unroll
            for (int i = 0; i < 4; ++i)
                #pragma unroll
                for (int jj = 0; jj < 4; ++jj)
                    acc[i][jj] = fmaf(a[i], b[jj], acc[i][jj]);
        }
    }

    #pragma unroll
    for (int i = 0; i < 4; ++i) {
        const size_t row = (size_t)(m0 + ty * 4 + i);
        #pragma unroll
        for (int jj = 0; jj < 4; ++jj) {
            const int col = n0 + tx * 4 + jj;
            C[row * NH + col] = acc[i][jj] + bias[col];
        }
    }
}

// ---------------------------------------------------------------------------
// Kernel 2: ZERO-SYNC scan with RESIDENT W.
// 1024 thr/chain (16 waves, 4/SIMD). Thread (j = tid&511, half = tid>>9)
// owns column j, k-range [256*half, 256*half+256) = 32 k-blocks (8 k each):
//   blocks  0..15 -> REGISTERS (16 named uint4 = 64 VGPR; 256 KB/CU)
//   blocks 16..23 -> LDS        (wlds, 128 KB, loaded once)
//   blocks 24..31 -> STREAMED from L2 each step (128 KB/step, ~0.9 us floor)
// Accumulation order 0..31 sequential == round-6 order (bit-identical sums).
// NOTE: wt3/out deliberately NOT __restrict__ -- the in-loop stores must
// may-alias the stream loads so LICM can't hoist them out of the t-loop
// (hoisting would demand 96 live W VGPRs -> spill). w00..w15 are loaded
// before the loop, so they stay in SSA registers regardless.
// ---------------------------------------------------------------------------
#define FMA8(WV, HA, HB)                                              \
    do {                                                              \
        acc = fmaf((HA).x, __uint_as_float((WV).x << 16),         acc); \
        acc = fmaf((HA).y, __uint_as_float((WV).x & 0xffff0000u), acc); \
        acc = fmaf((HA).z, __uint_as_float((WV).y << 16),         acc); \
        acc = fmaf((HA).w, __uint_as_float((WV).y & 0xffff0000u), acc); \
        acc = fmaf((HB).x, __uint_as_float((WV).z << 16),         acc); \
        acc = fmaf((HB).y, __uint_as_float((WV).z & 0xffff0000u), acc); \
        acc = fmaf((HB).z, __uint_as_float((WV).w << 16),         acc); \
        acc = fmaf((HB).w, __uint_as_float((WV).w & 0xffff0000u), acc); \
    } while (0)

__global__ __launch_bounds__(1024, 4) void rnn_scan_z3(
    const uint4* wt3,                // packed W_hh [64][512] uint4 (no restrict!)
    const float* __restrict__ H0,    // [128][512]
    float* out,                      // [128][2048][512] (no restrict!)
    float* hT)                       // [128][512] (aliases d_out region)
{
    __shared__ float h[2][NH];       // 4 KB double buffer
    __shared__ float ps[NH];         // 2 KB upper-half partials
    __shared__ uint4 wlds[16][NH];   // 128 KB resident W blocks

    const int tid  = threadIdx.x;
    const int b    = blockIdx.x;
    const int j    = tid & 511;
    const int half = tid >> 9;       // 0: k 0..255, 1: k 256..511

    // --- cooperative load of LDS-resident W blocks (global 16..23, 48..55) ---
    #pragma unroll
    for (int pass = 0; pass < 8; ++pass) {
        const int idx = pass * 1024 + tid;   // 0..8191 over [16][512]
        const int blk = idx >> 9;
        const int col = idx & 511;
        const int gb  = 16 + blk + ((blk >= 8) ? 24 : 0);  // 16..23, 48..55
        wlds[blk][col] = wt3[(size_t)gb * 512 + col];
    }

    // --- register-resident W blocks: this (j,half)'s blocks 0..15 ---
    const uint4* wreg = wt3 + (size_t)(half * 32) * 512 + j;
    const uint4 w00 = wreg[ 0 * 512], w01 = wreg[ 1 * 512];
    const uint4 w02 = wreg[ 2 * 512], w03 = wreg[ 3 * 512];
    const uint4 w04 = wreg[ 4 * 512], w05 = wreg[ 5 * 512];
    const uint4 w06 = wreg[ 6 * 512], w07 = wreg[ 7 * 512];
    const uint4 w08 = wreg[ 8 * 512], w09 = wreg[ 9 * 512];
    const uint4 w10 = wreg[10 * 512], w11 = wreg[11 * 512];
    const uint4 w12 = wreg[12 * 512], w13 = wreg[13 * 512];
    const uint4 w14 = wreg[14 * 512], w15 = wreg[15 * 512];

    if (half == 0) h[0][j] = H0[(size_t)b * NH + j];
    __syncthreads();   // wlds + h0 ready

    float* outrow = out + (size_t)b * T_SZ * NH + j;   // half 0 only
    float xp_cur = (half == 0) ? outrow[0] : 0.f;

    const uint4* wstr = wt3 + (size_t)(half * 32 + 24) * 512 + j;  // blocks 24..31
    const uint4* wldsp = &wlds[half * 8][j];                       // blocks 16..23
    const int hq_base = half * 64;
    int cur = 0;
    float hv = 0.0f;

    for (int t = 0; t < T_SZ; ++t) {
        // issue stream loads first; consumed LAST (reg/LDS FMAs cover latency)
        const uint4 s0 = wstr[0 * 512], s1 = wstr[1 * 512];
        const uint4 s2 = wstr[2 * 512], s3 = wstr[3 * 512];
        const uint4 s4 = wstr[4 * 512], s5 = wstr[5 * 512];
        const uint4 s6 = wstr[6 * 512], s7 = wstr[7 * 512];

        float xp_next = 0.f;
        if (half == 0 && t + 1 < T_SZ)
            xp_next = __builtin_nontemporal_load(outrow + (size_t)(t + 1) * NH);

        const float4* hq = reinterpret_cast<const float4*>(h[cur]) + hq_base;
        float acc = 0.0f;

        // blocks 0..15 from registers (h reads wave-uniform -> LDS broadcast)
        FMA8(w00, hq[ 0], hq[ 1]);  FMA8(w01, hq[ 2], hq[ 3]);
        FMA8(w02, hq[ 4], hq[ 5]);  FMA8(w03, hq[ 6], hq[ 7]);
        FMA8(w04, hq[ 8], hq[ 9]);  FMA8(w05, hq[10], hq[11]);
        FMA8(w06, hq[12], hq[13]);  FMA8(w07, hq[14], hq[15]);
        FMA8(w08, hq[16], hq[17]);  FMA8(w09, hq[18], hq[19]);
        FMA8(w10, hq[20], hq[21]);  FMA8(w11, hq[22], hq[23]);
        FMA8(w12, hq[24], hq[25]);  FMA8(w13, hq[26], hq[27]);
        FMA8(w14, hq[28], hq[29]);  FMA8(w15, hq[30], hq[31]);

        // blocks 16..23 from LDS
        #pragma unroll
        for (int q = 0; q < 8; ++q) {
            const uint4 wv = wldsp[q * 512];
            FMA8(wv, hq[32 + 2 * q], hq[33 + 2 * q]);
        }

        // blocks 24..31 from the in-flight stream loads
        FMA8(s0, hq[48], hq[49]);  FMA8(s1, hq[50], hq[51]);
        FMA8(s2, hq[52], hq[53]);  FMA8(s3, hq[54], hq[55]);
        FMA8(s4, hq[56], hq[57]);  FMA8(s5, hq[58], hq[59]);
        FMA8(s6, hq[60], hq[61]);  FMA8(s7, hq[62], hq[63]);

        if (half == 1) ps[j] = acc;
        __syncthreads();   // s1: partials visible
        if (half == 0) {
            hv = tanhf(acc + ps[j] + xp_cur);
            __builtin_nontemporal_store(hv, outrow + (size_t)t * NH);
            h[cur ^ 1][j] = hv;
            xp_cur = xp_next;
        }
        __syncthreads();   // s2: h[cur^1] complete before next dot
        cur ^= 1;
    }
    if (half == 0) hT[(size_t)b * NH + j] = hv;
}

// ---------------------------------------------------------------------------
extern "C" void kernel_launch(void* const* d_in, const int* in_sizes, int n_in,
                              void* d_out, int out_size, void* d_ws, size_t ws_size,
                              hipStream_t stream) {
    const float* inputs = (const float*)d_in[0];   // [B, T, NI]
    const float* H0     = (const float*)d_in[1];   // [B, NH]
    const float* W_xh   = (const float*)d_in[2];   // [NI, NH]
    const float* W_hh   = (const float*)d_in[3];   // [NH, NH]
    const float* b_h    = (const float*)d_in[4];   // [NH]

    float* out = (float*)d_out;                        // outs [B,T,NH]
    float* hT  = out + (size_t)B_SZ * T_SZ * NH;       // H_T [B,NH]

    uint4* wt3 = (uint4*)d_ws;                         // 512 KB packed W_hh

    // 0) pack W_hh -> bf16 pairs (deterministic, rewritten every launch)
    pack_whh<<<128, 256, 0, stream>>>(W_hh, wt3);

    // 1) input projection -> d_out outs region
    dim3 g1(NH / BN, (B_SZ * T_SZ) / BM);  // (8, 4096)
    proj_gemm<<<g1, 256, 0, stream>>>(inputs, W_xh, b_h, out);

    // 2) zero-sync recurrence: one 1024-thread WG per chain, resident W
    rnn_scan_z3<<<128, 1024, 0, stream>>>(wt3, H0, out, hT);
}